// Round 1
// baseline (51.581 us; speedup 1.0000x reference)
//
#include <hip/hip_runtime.h>
#include <hip/hip_bf16.h>
#include <stdint.h>

#define D_DIM 256
#define K_CTR 1024
#define B_ROWS 16384
#define BM 32

typedef __bf16 bf16x8 __attribute__((ext_vector_type(8)));
typedef float f32x4 __attribute__((ext_vector_type(4)));

static __device__ __forceinline__ unsigned short f2bf(float f) {
    return __builtin_bit_cast(unsigned short, __float2bfloat16(f));
}

// Prep: centers f32 -> bf16 (ws) + c_sq f32 (ws). 8 rows per block.
__global__ __launch_bounds__(256) void rbf_prep(const float* __restrict__ centers,
                                                unsigned short* __restrict__ cb,
                                                float* __restrict__ csq) {
    const int w = threadIdx.x >> 6;
    const int l = threadIdx.x & 63;
    const int base = blockIdx.x * 8;
    #pragma unroll
    for (int i = 0; i < 2; ++i) {
        const int row = base + i * 4 + w;
        const float4 v = *reinterpret_cast<const float4*>(centers + row * D_DIM + l * 4);
        float s = v.x * v.x + v.y * v.y + v.z * v.z + v.w * v.w;
        ushort4 p;
        p.x = f2bf(v.x); p.y = f2bf(v.y); p.z = f2bf(v.z); p.w = f2bf(v.w);
        *reinterpret_cast<ushort4*>(cb + row * D_DIM + l * 4) = p;
        #pragma unroll
        for (int off = 1; off < 64; off <<= 1) s += __shfl_xor(s, off);
        if (l == 0) csq[row] = s;
    }
}

// Main: each block computes 32 rows x 1024 cols.
// A (x strip) staged in LDS as bf16, XOR-swizzled. B fragments read from
// L2-resident bf16 centers directly (each wave load = 16 full 64B lines).
__global__ __launch_bounds__(256) void rbf_main(const float* __restrict__ x,
                                                const unsigned short* __restrict__ cb,
                                                const float* __restrict__ csq,
                                                const float* __restrict__ betas,
                                                float* __restrict__ out) {
    __shared__ __align__(16) unsigned short As[BM * D_DIM];  // 16 KB, swizzled
    __shared__ float xs_lds[BM];

    const int tid = threadIdx.x;
    const int w = tid >> 6;     // wave 0..3
    const int l = tid & 63;
    const int row0 = blockIdx.x * BM;

    // ---- Stage A: 8 iters; wave w loads row i*4+w, lane l -> float4 at col 4l ----
    #pragma unroll
    for (int i = 0; i < 8; ++i) {
        const int r = i * 4 + w;
        const float4 v = *reinterpret_cast<const float4*>(x + (row0 + r) * D_DIM + l * 4);
        float s = v.x * v.x + v.y * v.y + v.z * v.z + v.w * v.w;
        ushort4 p;
        p.x = f2bf(v.x); p.y = f2bf(v.y); p.z = f2bf(v.z); p.w = f2bf(v.w);
        const unsigned boff = (unsigned)((r * 512 + l * 8) ^ ((r & 7) << 4));
        *reinterpret_cast<ushort4*>(reinterpret_cast<char*>(As) + boff) = p;
        #pragma unroll
        for (int off = 1; off < 64; off <<= 1) s += __shfl_xor(s, off);
        if (l == 0) xs_lds[r] = s;
    }
    __syncthreads();

    const int hk = l >> 4;   // k-group 0..3
    const int lr = l & 15;   // row/col within fragment

    // Per-thread x_sq for the 8 output rows this thread touches.
    float xsq[2][4];
    #pragma unroll
    for (int m = 0; m < 2; ++m)
        #pragma unroll
        for (int j = 0; j < 4; ++j)
            xsq[m][j] = xs_lds[m * 16 + hk * 4 + j];

    // ---- 8 column tiles of 128 centers; wave covers 32 rows x 32 cols ----
    for (int ct = 0; ct < 8; ++ct) {
        const int colbase = ct * 128 + w * 32;
        f32x4 acc[2][2] = {};
        #pragma unroll
        for (int kk = 0; kk < 8; ++kk) {
            bf16x8 a[2], b[2];
            #pragma unroll
            for (int m = 0; m < 2; ++m) {
                const int r = m * 16 + lr;
                const unsigned boff = (unsigned)((r * 512 + kk * 64 + hk * 16) ^ ((r & 7) << 4));
                a[m] = *reinterpret_cast<const bf16x8*>(reinterpret_cast<const char*>(As) + boff);
            }
            #pragma unroll
            for (int n = 0; n < 2; ++n) {
                const int col = colbase + n * 16 + lr;
                b[n] = *reinterpret_cast<const bf16x8*>(
                    reinterpret_cast<const char*>(cb) + col * 512 + kk * 64 + hk * 16);
            }
            #pragma unroll
            for (int m = 0; m < 2; ++m)
                #pragma unroll
                for (int n = 0; n < 2; ++n)
                    acc[m][n] = __builtin_amdgcn_mfma_f32_16x16x32_bf16(a[m], b[n], acc[m][n], 0, 0, 0);
        }
        // ---- Epilogue: out = exp(-beta*(xsq + csq - 2*cross)) ----
        #pragma unroll
        for (int n = 0; n < 2; ++n) {
            const int col = colbase + n * 16 + lr;
            const float cs = csq[col];
            const float bt = betas[col];
            #pragma unroll
            for (int m = 0; m < 2; ++m) {
                const int rg = row0 + m * 16 + hk * 4;
                #pragma unroll
                for (int j = 0; j < 4; ++j) {
                    const float t = xsq[m][j] + cs - 2.0f * acc[m][n][j];
                    out[(rg + j) * K_CTR + col] = __expf(-bt * t);
                }
            }
        }
    }
}

extern "C" void kernel_launch(void* const* d_in, const int* in_sizes, int n_in,
                              void* d_out, int out_size, void* d_ws, size_t ws_size,
                              hipStream_t stream) {
    const float* x       = (const float*)d_in[0];
    const float* centers = (const float*)d_in[1];
    const float* betas   = (const float*)d_in[2];
    float* out = (float*)d_out;

    unsigned short* cb = (unsigned short*)d_ws;                       // 512 KB bf16 centers
    float* csq = (float*)((char*)d_ws + (size_t)K_CTR * D_DIM * 2);   // 4 KB c_sq

    rbf_prep<<<K_CTR / 8, 256, 0, stream>>>(centers, cb, csq);
    rbf_main<<<B_ROWS / BM, 256, 0, stream>>>(x, cb, csq, betas, out);
}

// Round 2
// 40.713 us; speedup vs baseline: 1.2669x; 1.2669x over previous
//
#include <hip/hip_runtime.h>
#include <hip/hip_bf16.h>
#include <stdint.h>

#define D_DIM 256
#define K_CTR 1024
#define B_ROWS 16384
#define BM 32
#define CSPLIT 2   // column split: each block does 32 rows x 512 cols

typedef __bf16 bf16x8 __attribute__((ext_vector_type(8)));
typedef float f32x4 __attribute__((ext_vector_type(4)));

static __device__ __forceinline__ unsigned short f2bf(float f) {
    return __builtin_bit_cast(unsigned short, __float2bfloat16(f));
}

// Prep: centers f32 -> bf16 in FRAGMENT-MAJOR layout + c_sq f32.
// Layout: 16-col group `colgrp`, chunk for (kk,hk,col&15) at byte
//   colgrp*8192 + kk*1024 + hk*256 + (col&15)*16
// so the main kernel's wave B-load (lane l = hk*16+lr) is one contiguous
// 1024B dwordx4: colgrp*8192 + kk*1024 + l*16.
__global__ __launch_bounds__(256) void rbf_prep(const float* __restrict__ centers,
                                                unsigned short* __restrict__ cbf,
                                                float* __restrict__ csq) {
    const int w = threadIdx.x >> 6;
    const int l = threadIdx.x & 63;
    const int base = blockIdx.x * 8;
    #pragma unroll
    for (int i = 0; i < 2; ++i) {
        const int row = base + i * 4 + w;          // center index (col in GEMM)
        const float4 v = *reinterpret_cast<const float4*>(centers + row * D_DIM + l * 4);
        float s = v.x * v.x + v.y * v.y + v.z * v.z + v.w * v.w;
        ushort4 p;
        p.x = f2bf(v.x); p.y = f2bf(v.y); p.z = f2bf(v.z); p.w = f2bf(v.w);
        // dims d = 4l..4l+3 -> kk = l>>3, hk = (l>>1)&3, byte-in-chunk = (l&1)*8
        char* dst = reinterpret_cast<char*>(cbf)
                  + (row >> 4) * 8192 + (l >> 3) * 1024 + ((l >> 1) & 3) * 256
                  + (row & 15) * 16 + (l & 1) * 8;
        *reinterpret_cast<ushort4*>(dst) = p;
        #pragma unroll
        for (int off = 1; off < 64; off <<= 1) s += __shfl_xor(s, off);
        if (l == 0) csq[row] = s;
    }
}

// Main: block = 32 rows x 512 cols. A strip in LDS (bf16, XOR-swizzled);
// B fragments from L2-resident fragment-major cbf (coalesced 1KB loads).
__global__ __launch_bounds__(256) void rbf_main(const float* __restrict__ x,
                                                const unsigned short* __restrict__ cbf,
                                                const float* __restrict__ csq,
                                                const float* __restrict__ betas,
                                                float* __restrict__ out) {
    __shared__ __align__(16) unsigned short As[BM * D_DIM];  // 16 KB, swizzled
    __shared__ float xs_lds[BM];

    const int tid = threadIdx.x;
    const int w = tid >> 6;     // wave 0..3
    const int l = tid & 63;
    const int bid = blockIdx.x;
    const int strip = bid & (B_ROWS / BM - 1);   // bid & 511
    const int cidx  = bid >> 9;                   // 0 / 1 -> col half
    const int row0 = strip * BM;

    // ---- Stage A: wave w loads row i*4+w, lane l -> float4 at col 4l ----
    #pragma unroll
    for (int i = 0; i < 8; ++i) {
        const int r = i * 4 + w;
        const float4 v = *reinterpret_cast<const float4*>(x + (row0 + r) * D_DIM + l * 4);
        float s = v.x * v.x + v.y * v.y + v.z * v.z + v.w * v.w;
        ushort4 p;
        p.x = f2bf(v.x); p.y = f2bf(v.y); p.z = f2bf(v.z); p.w = f2bf(v.w);
        const unsigned boff = (unsigned)((r * 512 + l * 8) ^ ((r & 7) << 4));
        *reinterpret_cast<ushort4*>(reinterpret_cast<char*>(As) + boff) = p;
        #pragma unroll
        for (int off = 1; off < 64; off <<= 1) s += __shfl_xor(s, off);
        if (l == 0) xs_lds[r] = s;
    }
    __syncthreads();

    const int hk = l >> 4;   // k-group 0..3
    const int lr = l & 15;   // row/col within fragment

    float xsq[2][4];
    #pragma unroll
    for (int m = 0; m < 2; ++m)
        #pragma unroll
        for (int j = 0; j < 4; ++j)
            xsq[m][j] = xs_lds[m * 16 + hk * 4 + j];

    // ---- 4 column tiles of 128; wave covers 32 rows x 32 cols per tile ----
    #pragma unroll 1
    for (int ct = 0; ct < 4; ++ct) {
        const int colbase = cidx * 512 + ct * 128 + w * 32;
        f32x4 acc[2][2] = {};
        #pragma unroll
        for (int kk = 0; kk < 8; ++kk) {
            bf16x8 a[2], b[2];
            #pragma unroll
            for (int m = 0; m < 2; ++m) {
                const int r = m * 16 + lr;
                const unsigned boff = (unsigned)((r * 512 + kk * 64 + hk * 16) ^ ((r & 7) << 4));
                a[m] = *reinterpret_cast<const bf16x8*>(reinterpret_cast<const char*>(As) + boff);
            }
            #pragma unroll
            for (int n = 0; n < 2; ++n) {
                const int colgrp = (colbase >> 4) + n;
                b[n] = *reinterpret_cast<const bf16x8*>(
                    reinterpret_cast<const char*>(cbf) + colgrp * 8192 + kk * 1024 + l * 16);
            }
            #pragma unroll
            for (int m = 0; m < 2; ++m)
                #pragma unroll
                for (int n = 0; n < 2; ++n)
                    acc[m][n] = __builtin_amdgcn_mfma_f32_16x16x32_bf16(a[m], b[n], acc[m][n], 0, 0, 0);
        }
        // ---- Epilogue: out = exp(-beta*(xsq + csq - 2*cross)) ----
        #pragma unroll
        for (int n = 0; n < 2; ++n) {
            const int col = colbase + n * 16 + lr;
            const float cs = csq[col];
            const float bt = betas[col];
            #pragma unroll
            for (int m = 0; m < 2; ++m) {
                const int rg = row0 + m * 16 + hk * 4;
                #pragma unroll
                for (int j = 0; j < 4; ++j) {
                    const float t = xsq[m][j] + cs - 2.0f * acc[m][n][j];
                    out[(rg + j) * K_CTR + col] = __expf(-bt * t);
                }
            }
        }
    }
}

extern "C" void kernel_launch(void* const* d_in, const int* in_sizes, int n_in,
                              void* d_out, int out_size, void* d_ws, size_t ws_size,
                              hipStream_t stream) {
    const float* x       = (const float*)d_in[0];
    const float* centers = (const float*)d_in[1];
    const float* betas   = (const float*)d_in[2];
    float* out = (float*)d_out;

    unsigned short* cbf = (unsigned short*)d_ws;                      // 512 KB bf16 centers (fragment-major)
    float* csq = (float*)((char*)d_ws + (size_t)K_CTR * D_DIM * 2);   // 4 KB c_sq

    rbf_prep<<<K_CTR / 8, 256, 0, stream>>>(centers, cbf, csq);
    rbf_main<<<(B_ROWS / BM) * CSPLIT, 256, 0, stream>>>(x, cbf, csq, betas, out);
}